// Round 1
// baseline (864.763 us; speedup 1.0000x reference)
//
#include <hip/hip_runtime.h>

// OctreeMaxPool: data [C=128, N] fp32, child_idx [M] int32 (-1 => empty).
// out [C, M]: out[c,m] = idx>=0 ? max over 8 children data[c, 8*idx .. 8*idx+7] : 0.
//
// One thread per parent node m; grid.y tiles channels in groups of 8.
// Non-empty lanes gather 2x float4 (32B aligned) per channel; empty lanes
// write zeros without reading data (halves gather traffic; worth the
// wave divergence since we're HBM-bound).

#define CH 128
#define CH_PER_BLOCK 8

__global__ __launch_bounds__(256) void octree_maxpool_kernel(
    const float* __restrict__ data,
    const int* __restrict__ child_idx,
    float* __restrict__ out,
    int n,        // N (children count)
    int m_total)  // M (parent count)
{
    int m = blockIdx.x * 256 + threadIdx.x;
    if (m >= m_total) return;

    int idx = child_idx[m];
    int c0 = blockIdx.y * CH_PER_BLOCK;

    if (idx < 0) {
        // empty parent: zero-fill (d_out is poisoned, must write)
        #pragma unroll
        for (int cc = 0; cc < CH_PER_BLOCK; ++cc) {
            out[(size_t)(c0 + cc) * m_total + m] = 0.0f;
        }
        return;
    }

    size_t base = (size_t)idx * 8;
    #pragma unroll
    for (int cc = 0; cc < CH_PER_BLOCK; ++cc) {
        const float4* p = (const float4*)(data + (size_t)(c0 + cc) * n + base);
        float4 a = p[0];
        float4 b = p[1];
        float v = fmaxf(fmaxf(fmaxf(a.x, a.y), fmaxf(a.z, a.w)),
                        fmaxf(fmaxf(b.x, b.y), fmaxf(b.z, b.w)));
        out[(size_t)(c0 + cc) * m_total + m] = v;
    }
}

extern "C" void kernel_launch(void* const* d_in, const int* in_sizes, int n_in,
                              void* d_out, int out_size, void* d_ws, size_t ws_size,
                              hipStream_t stream) {
    const float* data      = (const float*)d_in[0];
    const int*   child_idx = (const int*)d_in[1];
    float*       out       = (float*)d_out;

    int n = in_sizes[0] / CH;   // N = 1048576
    int m = in_sizes[1];        // M = 262144

    dim3 block(256, 1, 1);
    dim3 grid((m + 255) / 256, CH / CH_PER_BLOCK, 1);
    hipLaunchKernelGGL(octree_maxpool_kernel, grid, block, 0, stream,
                       data, child_idx, out, n, m);
}

// Round 2
// 833.635 us; speedup vs baseline: 1.0373x; 1.0373x over previous
//
#include <hip/hip_runtime.h>

// OctreeMaxPool, two-pass:
//   Pass 1: pooled[c,g] = max over data[c, 8g..8g+7]   (streaming, coalesced)
//   Pass 2: out[c,m]   = idx[m]>=0 ? pooled[c, idx[m]] : 0
// pooled (64 MB) lives in d_ws and is LLC-resident for pass 2's random gather,
// turning ~2.1 GB of uncoalesced HBM gather (fused version, R1: 865 us) into
// 512 MB of sequential reads + an LLC-served gather.

#define CH 128
#define CH_PER_BLOCK 8

// ---------------- Pass 1: segmented max over 8 consecutive ----------------
__global__ __launch_bounds__(256) void pool_kernel(
    const float* __restrict__ data,
    float* __restrict__ pooled,
    int total_groups)   // C * N/8
{
    int g = blockIdx.x * 256 + threadIdx.x;
    if (g >= total_groups) return;
    const float4* p = (const float4*)(data + (size_t)g * 8);
    float4 a = p[0];
    float4 b = p[1];
    pooled[g] = fmaxf(fmaxf(fmaxf(a.x, a.y), fmaxf(a.z, a.w)),
                      fmaxf(fmaxf(b.x, b.y), fmaxf(b.z, b.w)));
}

// ---------------- Pass 2: gather + zero-pad ----------------
__global__ __launch_bounds__(256) void pad_kernel(
    const float* __restrict__ pooled,
    const int* __restrict__ child_idx,
    float* __restrict__ out,
    int groups_per_ch,  // N/8
    int m_total)        // M
{
    int m = blockIdx.x * 256 + threadIdx.x;
    if (m >= m_total) return;
    int idx = child_idx[m];
    int c0 = blockIdx.y * CH_PER_BLOCK;

    if (idx < 0) {
        #pragma unroll
        for (int cc = 0; cc < CH_PER_BLOCK; ++cc)
            out[(size_t)(c0 + cc) * m_total + m] = 0.0f;
    } else {
        #pragma unroll
        for (int cc = 0; cc < CH_PER_BLOCK; ++cc)
            out[(size_t)(c0 + cc) * m_total + m] =
                pooled[(size_t)(c0 + cc) * groups_per_ch + idx];
    }
}

// ---------------- Fallback: fused single-pass (R1 kernel) ----------------
__global__ __launch_bounds__(256) void fused_kernel(
    const float* __restrict__ data,
    const int* __restrict__ child_idx,
    float* __restrict__ out,
    int n, int m_total)
{
    int m = blockIdx.x * 256 + threadIdx.x;
    if (m >= m_total) return;
    int idx = child_idx[m];
    int c0 = blockIdx.y * CH_PER_BLOCK;
    if (idx < 0) {
        #pragma unroll
        for (int cc = 0; cc < CH_PER_BLOCK; ++cc)
            out[(size_t)(c0 + cc) * m_total + m] = 0.0f;
        return;
    }
    size_t base = (size_t)idx * 8;
    #pragma unroll
    for (int cc = 0; cc < CH_PER_BLOCK; ++cc) {
        const float4* p = (const float4*)(data + (size_t)(c0 + cc) * n + base);
        float4 a = p[0];
        float4 b = p[1];
        out[(size_t)(c0 + cc) * m_total + m] =
            fmaxf(fmaxf(fmaxf(a.x, a.y), fmaxf(a.z, a.w)),
                  fmaxf(fmaxf(b.x, b.y), fmaxf(b.z, b.w)));
    }
}

extern "C" void kernel_launch(void* const* d_in, const int* in_sizes, int n_in,
                              void* d_out, int out_size, void* d_ws, size_t ws_size,
                              hipStream_t stream) {
    const float* data      = (const float*)d_in[0];
    const int*   child_idx = (const int*)d_in[1];
    float*       out       = (float*)d_out;

    int n = in_sizes[0] / CH;       // N = 1048576
    int m = in_sizes[1];            // M = 262144
    int gpc = n / 8;                // groups per channel
    int total_groups = CH * gpc;    // 16.7M
    size_t pooled_bytes = (size_t)total_groups * sizeof(float);

    if (ws_size >= pooled_bytes) {
        float* pooled = (float*)d_ws;
        dim3 b1(256), g1((total_groups + 255) / 256);
        hipLaunchKernelGGL(pool_kernel, g1, b1, 0, stream, data, pooled, total_groups);
        dim3 b2(256), g2((m + 255) / 256, CH / CH_PER_BLOCK);
        hipLaunchKernelGGL(pad_kernel, g2, b2, 0, stream, pooled, child_idx, out, gpc, m);
    } else {
        dim3 b(256), g((m + 255) / 256, CH / CH_PER_BLOCK);
        hipLaunchKernelGGL(fused_kernel, g, b, 0, stream, data, child_idx, out, n, m);
    }
}

// Round 3
// 805.248 us; speedup vs baseline: 1.0739x; 1.0353x over previous
//
#include <hip/hip_runtime.h>

// OctreeMaxPool, two-pass with TRANSPOSED intermediate:
//   Pass 1: pooled_t[g*128 + c] = max over data[c, 8g..8g+7]
//   Pass 2: out[c,m] = idx[m]>=0 ? pooled_t[idx[m]*128 + c] : 0
//
// Group-major pooled_t makes each parent's 128 channels one contiguous 512 B
// record, so pass 2's random gather reads whole 128 B lines (100% utilized)
// instead of 4 B out of each line (R2 version: ~2.1 GB of line-granular L2/LLC
// traffic for 67 MB useful). pooled_t (64 MB) stays LLC-resident from pass 1.

#define CH 128

// ---------------- Pass 1: pool + transpose (no LDS) ----------------
// Block 256 = 8 groups x 32 channel-quads.
//   reads:  per instr, 32 channel-rows x 256 B dense segments (fully coalesced)
//   writes: lanes 0..31 cover one group's 512 B record (fully coalesced)
__global__ __launch_bounds__(256) void pool_t_kernel(
    const float* __restrict__ data,
    float* __restrict__ pooled_t,
    int n,     // N
    int gpc)   // N/8
{
    int t  = threadIdx.x;
    int gl = t >> 5;                 // 0..7   group within block
    int cq = t & 31;                 // 0..31  channel quad
    int g  = blockIdx.x * 8 + gl;
    if (g >= gpc) return;
    int c0 = cq * 4;

    const float* base = data + (size_t)g * 8;
    float v[4];
    #pragma unroll
    for (int k = 0; k < 4; ++k) {
        const float4* p = (const float4*)(base + (size_t)(c0 + k) * n);
        float4 a = p[0];
        float4 b = p[1];
        v[k] = fmaxf(fmaxf(fmaxf(a.x, a.y), fmaxf(a.z, a.w)),
                     fmaxf(fmaxf(b.x, b.y), fmaxf(b.z, b.w)));
    }
    *(float4*)(pooled_t + (size_t)g * CH + c0) = make_float4(v[0], v[1], v[2], v[3]);
}

// ---------------- Pass 2: record gather + zero-pad ----------------
// Thread per m; grid.y = 4 channel quarters (32 ch each). Non-empty lanes
// read one aligned 128 B chunk of the 512 B record (8x float4, same line);
// writes coalesced along m.
__global__ __launch_bounds__(256) void pad_t_kernel(
    const float* __restrict__ pooled_t,
    const int* __restrict__ child_idx,
    float* __restrict__ out,
    int m_total)
{
    int m = blockIdx.x * 256 + threadIdx.x;
    if (m >= m_total) return;
    int idx = child_idx[m];
    int c0 = blockIdx.y * 32;

    if (idx < 0) {
        #pragma unroll
        for (int k = 0; k < 32; ++k)
            out[(size_t)(c0 + k) * m_total + m] = 0.0f;
        return;
    }

    const float4* rec = (const float4*)(pooled_t + (size_t)idx * CH + c0);
    float4 v[8];
    #pragma unroll
    for (int k = 0; k < 8; ++k) v[k] = rec[k];
    #pragma unroll
    for (int k = 0; k < 8; ++k) {
        out[(size_t)(c0 + 4 * k + 0) * m_total + m] = v[k].x;
        out[(size_t)(c0 + 4 * k + 1) * m_total + m] = v[k].y;
        out[(size_t)(c0 + 4 * k + 2) * m_total + m] = v[k].z;
        out[(size_t)(c0 + 4 * k + 3) * m_total + m] = v[k].w;
    }
}

// ---------------- Fallback: fused single-pass (R1 kernel) ----------------
__global__ __launch_bounds__(256) void fused_kernel(
    const float* __restrict__ data,
    const int* __restrict__ child_idx,
    float* __restrict__ out,
    int n, int m_total)
{
    int m = blockIdx.x * 256 + threadIdx.x;
    if (m >= m_total) return;
    int idx = child_idx[m];
    int c0 = blockIdx.y * 8;
    if (idx < 0) {
        #pragma unroll
        for (int cc = 0; cc < 8; ++cc)
            out[(size_t)(c0 + cc) * m_total + m] = 0.0f;
        return;
    }
    size_t base = (size_t)idx * 8;
    #pragma unroll
    for (int cc = 0; cc < 8; ++cc) {
        const float4* p = (const float4*)(data + (size_t)(c0 + cc) * n + base);
        float4 a = p[0];
        float4 b = p[1];
        out[(size_t)(c0 + cc) * m_total + m] =
            fmaxf(fmaxf(fmaxf(a.x, a.y), fmaxf(a.z, a.w)),
                  fmaxf(fmaxf(b.x, b.y), fmaxf(b.z, b.w)));
    }
}

extern "C" void kernel_launch(void* const* d_in, const int* in_sizes, int n_in,
                              void* d_out, int out_size, void* d_ws, size_t ws_size,
                              hipStream_t stream) {
    const float* data      = (const float*)d_in[0];
    const int*   child_idx = (const int*)d_in[1];
    float*       out       = (float*)d_out;

    int n   = in_sizes[0] / CH;     // N = 1048576
    int m   = in_sizes[1];          // M = 262144
    int gpc = n / 8;                // 131072
    size_t pooled_bytes = (size_t)gpc * CH * sizeof(float);  // 64 MB

    if (ws_size >= pooled_bytes) {
        float* pooled_t = (float*)d_ws;
        dim3 b1(256), g1((gpc + 7) / 8);
        hipLaunchKernelGGL(pool_t_kernel, g1, b1, 0, stream, data, pooled_t, n, gpc);
        dim3 b2(256), g2((m + 255) / 256, 4);
        hipLaunchKernelGGL(pad_t_kernel, g2, b2, 0, stream, pooled_t, child_idx, out, m);
    } else {
        dim3 b(256), g((m + 255) / 256, CH / 8);
        hipLaunchKernelGGL(fused_kernel, g, b, 0, stream, data, child_idx, out, n, m);
    }
}